// Round 3
// baseline (978.311 us; speedup 1.0000x reference)
//
#include <hip/hip_runtime.h>

// Problem constants (fixed by setup_inputs)
#define B_    8
#define CIN   3
#define H_    512
#define W_    512
#define COUT  64
#define E_    3
#define HW_   (H_ * W_)

typedef float v4f __attribute__((ext_vector_type(4)));

// R2 restructure: 8 px/thread (was 4). One block: batch b (= blockIdx.x & 7,
// XCD round-robin affinity), 4 output rows, full width, all 64 channels.
// 256 threads: tid>>6 = row (0..3), tid&63 = 8-px segment. Thread keeps the
// 3(ci) x 3(kh) x 10(w) input window in VGPRs (~90 regs) and loops channels;
// weights are wave-uniform -> s_load; per-channel FMA block = 216 FMAs vs
// ~25 overhead ops (2x better amortization than the 4-px version), and
// per-channel contiguous write chunk doubles to 8 KB.
__global__ __launch_bounds__(256, 4)
void conv_fused(const float* __restrict__ x,
                const float* __restrict__ vin,    // extra_inputs [B, COUT*E]
                const float* __restrict__ wm,     // w_main [COUT, CIN, 3, 3]
                const float* __restrict__ bm,     // b_main [COUT]
                const float* __restrict__ we,     // w_extra [COUT, E, 3, 3]
                const float* __restrict__ be,     // b_extra [COUT]
                float* __restrict__ out)          // [B, COUT, H, W]
{
    // Per-(b,c) summaries of the constant "extra" conv contribution:
    // Cfull = b_main + b_extra + sum of all 9 wc taps (interior value)
    // R0/R2 = top/bottom row tap-sums, C0/C2 = left/right col tap-sums,
    // K** = corner taps (add back double-subtracted corners).
    __shared__ float sCfull[COUT], sR0[COUT], sR2[COUT], sC0[COUT], sC2[COUT],
                     sK00[COUT], sK02[COUT], sK20[COUT], sK22[COUT];

    const int b   = blockIdx.x & 7;    // 8 batches <-> 8 XCDs
    const int til = blockIdx.x >> 3;   // 0..127 row tiles (4 rows each)
    const int tid = threadIdx.x;

    if (tid < COUT) {
        const int c = tid;
        const float* wep = we + c * (E_ * 9);
        const float v0 = vin[b * (COUT * E_) + c * E_ + 0];
        const float v1 = vin[b * (COUT * E_) + c * E_ + 1];
        const float v2 = vin[b * (COUT * E_) + c * E_ + 2];
        float wc[9];
        #pragma unroll
        for (int t = 0; t < 9; ++t)
            wc[t] = v0 * wep[t] + v1 * wep[9 + t] + v2 * wep[18 + t];
        float s9 = 0.f;
        #pragma unroll
        for (int t = 0; t < 9; ++t) s9 += wc[t];
        sCfull[c] = bm[c] + be[c] + s9;
        sR0[c] = wc[0] + wc[1] + wc[2];
        sR2[c] = wc[6] + wc[7] + wc[8];
        sC0[c] = wc[0] + wc[3] + wc[6];
        sC2[c] = wc[2] + wc[5] + wc[8];
        sK00[c] = wc[0]; sK02[c] = wc[2]; sK20[c] = wc[6]; sK22[c] = wc[8];
    }
    __syncthreads();

    const int row  = tid >> 6;       // 0..3 (wave-uniform)
    const int seg  = tid & 63;       // 0..63
    const int w0   = seg << 3;       // 0,8,...,504
    const int h    = til * 4 + row;  // 0..511

    // Load the input neighborhood once: xr[ci][kh][t] = x[b,ci,h+kh-1,w0-1+t],
    // zero for out-of-range (matches zero padding). w0 is 32B-aligned -> two
    // aligned float4 loads + 2 edge scalars per (ci,kh).
    float xr[CIN][3][10];
    #pragma unroll
    for (int ci = 0; ci < CIN; ++ci) {
        #pragma unroll
        for (int kh = 0; kh < 3; ++kh) {
            const int y = h + kh - 1;
            if ((unsigned)y < (unsigned)H_) {
                const float* rp = x + ((size_t)(b * CIN + ci) * H_ + y) * W_;
                const v4f m0 = *(const v4f*)(rp + w0);
                const v4f m1 = *(const v4f*)(rp + w0 + 4);
                xr[ci][kh][1] = m0.x; xr[ci][kh][2] = m0.y;
                xr[ci][kh][3] = m0.z; xr[ci][kh][4] = m0.w;
                xr[ci][kh][5] = m1.x; xr[ci][kh][6] = m1.y;
                xr[ci][kh][7] = m1.z; xr[ci][kh][8] = m1.w;
                xr[ci][kh][0] = (seg > 0)  ? rp[w0 - 1] : 0.f;
                xr[ci][kh][9] = (seg < 63) ? rp[w0 + 8] : 0.f;
            } else {
                #pragma unroll
                for (int t = 0; t < 10; ++t) xr[ci][kh][t] = 0.f;
            }
        }
    }

    const bool htop = (h == 0), hbot = (h == H_ - 1);   // wave-uniform
    const bool wlft = (seg == 0), wrgt = (seg == 63);   // 1 lane each
    float* outp = out + ((size_t)(b * COUT) * H_ + h) * W_ + w0;

    #pragma unroll 1
    for (int c = 0; c < COUT; ++c) {
        const int cu = __builtin_amdgcn_readfirstlane(c);   // uniform -> s_load weights
        const float* wp = wm + cu * 27;

        float base = sCfull[cu];
        if (htop) base -= sR0[cu];
        if (hbot) base -= sR2[cu];
        float a[8];
        #pragma unroll
        for (int p = 0; p < 8; ++p) a[p] = base;
        if (wlft) {  // pixel w==0 lives at a[0]
            a[0] -= sC0[cu];
            if (htop) a[0] += sK00[cu];
            if (hbot) a[0] += sK20[cu];
        }
        if (wrgt) {  // pixel w==511 lives at a[7]
            a[7] -= sC2[cu];
            if (htop) a[7] += sK02[cu];
            if (hbot) a[7] += sK22[cu];
        }

        #pragma unroll
        for (int ci = 0; ci < CIN; ++ci) {
            #pragma unroll
            for (int kh = 0; kh < 3; ++kh) {
                #pragma unroll
                for (int kw = 0; kw < 3; ++kw) {
                    const float wv = wp[ci * 9 + kh * 3 + kw];
                    #pragma unroll
                    for (int p = 0; p < 8; ++p)
                        a[p] += xr[ci][kh][kw + p] * wv;
                }
            }
        }

        float* op = outp + (size_t)cu * HW_;
        v4f o0; o0.x = a[0]; o0.y = a[1]; o0.z = a[2]; o0.w = a[3];
        v4f o1; o1.x = a[4]; o1.y = a[5]; o1.z = a[6]; o1.w = a[7];
        *(v4f*)(op)     = o0;
        *(v4f*)(op + 4) = o1;
    }
}

extern "C" void kernel_launch(void* const* d_in, const int* in_sizes, int n_in,
                              void* d_out, int out_size, void* d_ws, size_t ws_size,
                              hipStream_t stream) {
    const float* x   = (const float*)d_in[0];
    const float* vin = (const float*)d_in[1];
    const float* wmn = (const float*)d_in[2];
    const float* bmn = (const float*)d_in[3];
    const float* wex = (const float*)d_in[4];
    const float* bex = (const float*)d_in[5];
    float* out = (float*)d_out;

    const int blocks = B_ * (H_ / 4);  // 1024
    conv_fused<<<blocks, 256, 0, stream>>>(x, vin, wmn, bmn, wex, bex, out);
}